// Round 4
// baseline (1310.681 us; speedup 1.0000x reference)
//
#include <hip/hip_runtime.h>
#include <hip/hip_bf16.h>
#include <math.h>

#define NROWS 131072
#define E 1024
#define L 512
#define DD 256
#define NI 50
#define CAP 2048
#define NBINS 16384

typedef __attribute__((ext_vector_type(8))) short bf16x8;
typedef __attribute__((ext_vector_type(4))) float f32x4;

__device__ __forceinline__ unsigned short f2bf(float f) {
  unsigned u = __float_as_uint(f);
  unsigned r = (u + 0x7FFFu + ((u >> 16) & 1u)) >> 16;   // RNE
  return (unsigned short)r;
}
__device__ __forceinline__ float bf2f(unsigned short b) {
  return __uint_as_float(((unsigned)b) << 16);
}
__device__ __forceinline__ float frcp(float x) { return __builtin_amdgcn_rcpf(x); }
__device__ __forceinline__ float fsig(float x) { return frcp(1.0f + __expf(-x)); }
__device__ __forceinline__ float ftanh(float x) { return 2.0f * frcp(1.0f + __expf(-2.0f * x)) - 1.0f; }
__device__ __forceinline__ unsigned encf(float f) {
  unsigned u = __float_as_uint(f);
  return (u & 0x80000000u) ? ~u : (u | 0x80000000u);
}
__device__ __forceinline__ float decf(unsigned e) {
  unsigned b = (e & 0x80000000u) ? (e & 0x7FFFFFFFu) : ~e;
  return __uint_as_float(b);
}
// packed fp32x2 -> bf16x2 (RNE), low short = first operand
__device__ __forceinline__ unsigned cvtpk(float a, float b) {
  unsigned r;
  asm("v_cvt_pk_bf16_f32 %0, %1, %2" : "=v"(r) : "v"(a), "v"(b));
  return r;
}

#define GLDS16(gp, lp)                                                        \
  __builtin_amdgcn_global_load_lds(                                           \
      (const __attribute__((address_space(1))) void*)(gp),                    \
      (__attribute__((address_space(3))) void*)(lp), 16, 0, 0)

// ---------------------------------------------------------------- K0: init
__global__ void k0_init(const float* __restrict__ Wc, const float* __restrict__ Wv,
                        const float* __restrict__ Wu,
                        unsigned short* __restrict__ WcB, unsigned short* __restrict__ W2B,
                        float* __restrict__ Aws, float* __restrict__ tws,
                        unsigned* __restrict__ hist,
                        float* __restrict__ scalF, unsigned* __restrict__ scalU) {
  const int i0 = blockIdx.x * blockDim.x + threadIdx.x;
  const int str = gridDim.x * blockDim.x;
  if (i0 < 4) scalF[i0] = 0.f;
  if (i0 < 16) scalU[i0] = (i0 == 0) ? 0xFFFFFFFFu : 0u;
  for (int k = i0; k < NBINS; k += str) hist[k] = 0u;
  for (int k = i0; k < NROWS * 2; k += str) { Aws[k] = 0.f; tws[k] = 0.f; }
  for (int k = i0; k < L * E; k += str) WcB[k] = f2bf(Wc[k]);
  for (int k = i0; k < DD * L; k += str) { W2B[k] = f2bf(Wv[k]); W2B[DD * L + k] = f2bf(Wu[k]); }
}

// ------------- K1: h = relu(x @ Wc^T + bc); also t = h @ Wbag^T (partial, atomic)
// 128 rows x 256 cols, BK=64 (16 K-steps), 4 waves (2x2 of 64x128).
// DOUBLE-BUFFERED: stage tile t+1 (async global_load_lds) before computing tile t;
// single __syncthreads() per K-step (its implicit vmcnt(0) drains loads that had the
// whole compute phase in flight).  x staged fp32 (16-slot swizzle), wt bf16 (8-slot).
// LDS = 2*(32+32) = 128KB -> 1 block/CU.
__global__ __launch_bounds__(256) void k1_gemm1(const float* __restrict__ x,
                                                const unsigned short* __restrict__ WcB,
                                                const float* __restrict__ bc,
                                                const float* __restrict__ Wbag,
                                                unsigned short* __restrict__ hB,
                                                float* __restrict__ tws) {
  __shared__ __align__(16) float xs[2][128 * 64];            // 2 x 32KB fp32
  __shared__ __align__(16) unsigned short wt[2][256 * 64];   // 2 x 32KB bf16
  const int tid = threadIdx.x;
  const int lane = tid & 63;
  const int wv = tid >> 6;
  const int cbk = blockIdx.x & 1;
  const int rbk = blockIdx.x >> 1;
  const int row0 = rbk << 7;
  const int col0 = cbk << 8;
  const int wr = wv >> 1, wc = wv & 1;
  const int q = lane >> 4, c15 = lane & 15;

  f32x4 acc[4][8];
#pragma unroll
  for (int i = 0; i < 4; ++i)
#pragma unroll
    for (int j = 0; j < 8; ++j) acc[i][j] = {0.f, 0.f, 0.f, 0.f};

#define K1_STAGE(B, KK)                                                        \
  {                                                                            \
    _Pragma("unroll")                                                          \
    for (int i = 0; i < 8; ++i) {                                              \
      const int g = (wv << 3) + i;                                             \
      const int j = (g << 2) + (lane >> 4);                                    \
      const int s = lane & 15;                                                 \
      const int s4 = (s ^ (j & 15)) << 2;                                      \
      GLDS16(x + (size_t)(row0 + j) * E + (KK) + s4, &xs[B][g << 8]);          \
    }                                                                          \
    _Pragma("unroll")                                                          \
    for (int i = 0; i < 8; ++i) {                                              \
      const int g = (wv << 3) + i;                                             \
      const int slot = (g << 6) + lane;                                        \
      const int j = slot >> 3;                                                 \
      const int s = slot & 7;                                                  \
      const int k8 = s ^ (j & 7);                                              \
      GLDS16(WcB + (size_t)(col0 + j) * E + (KK) + (k8 << 3), &wt[B][g << 9]); \
    }                                                                          \
  }

  K1_STAGE(0, 0);
  __syncthreads();

  for (int t = 0; t < 16; ++t) {
    const int cur = t & 1;
    if (t < 15) K1_STAGE(cur ^ 1, (t + 1) << 6);
    const float* xsb = xs[cur];
    const unsigned short* wtb = wt[cur];
#pragma unroll
    for (int ks = 0; ks < 2; ++ks) {
      const int ch = (ks << 2) + q;                      // k-chunk 0..7 (8 f32 each)
      union { bf16x8 v; unsigned u[4]; } af[4];
#pragma unroll
      for (int mt = 0; mt < 4; ++mt) {
        const int rr = (wr << 6) + (mt << 4) + c15;
        const int r15 = rr & 15;
        const f32x4 lo = *(const f32x4*)(xsb + (rr << 6) + ((((ch << 1)    ) ^ r15) << 2));
        const f32x4 hi = *(const f32x4*)(xsb + (rr << 6) + ((((ch << 1) | 1) ^ r15) << 2));
        af[mt].u[0] = cvtpk(lo[0], lo[1]);
        af[mt].u[1] = cvtpk(lo[2], lo[3]);
        af[mt].u[2] = cvtpk(hi[0], hi[1]);
        af[mt].u[3] = cvtpk(hi[2], hi[3]);
      }
#pragma unroll
      for (int nt = 0; nt < 8; ++nt) {
        const int jj = (wc << 7) + (nt << 4) + c15;
        const bf16x8 bb = *(const bf16x8*)(wtb + (jj << 6) + ((ch ^ (jj & 7)) << 3));
#pragma unroll
        for (int mt = 0; mt < 4; ++mt)
          acc[mt][nt] = __builtin_amdgcn_mfma_f32_16x16x32_bf16(af[mt].v, bb, acc[mt][nt], 0, 0, 0);
      }
    }
    __syncthreads();
  }
  // epilogue: bias+relu, bag-dot partial, bf16 pack-pairs + dword stores
  float bias[8], wb0[8], wb1[8];
#pragma unroll
  for (int nt = 0; nt < 8; ++nt) {
    const int colg = col0 + (wc << 7) + (nt << 4) + c15;
    bias[nt] = bc[colg];
    wb0[nt] = Wbag[colg];
    wb1[nt] = Wbag[L + colg];
  }
#pragma unroll
  for (int mt = 0; mt < 4; ++mt) {
#pragma unroll
    for (int r = 0; r < 4; ++r) {
      const int rowg = row0 + (wr << 6) + (mt << 4) + (q << 2) + r;
      float tp0 = 0.f, tp1 = 0.f;
#pragma unroll
      for (int nt = 0; nt < 8; ++nt) {
        const int colg = col0 + (wc << 7) + (nt << 4) + c15;
        float v = acc[mt][nt][r] + bias[nt];
        v = v > 0.f ? v : 0.f;
        tp0 += v * wb0[nt];
        tp1 += v * wb1[nt];
        const unsigned short hb = f2bf(v);
        const unsigned short ob = (unsigned short)__shfl_xor((int)hb, 1, 64);
        if (!(lane & 1)) {
          *(unsigned*)(hB + (size_t)rowg * L + colg) = (unsigned)hb | ((unsigned)ob << 16);
        }
      }
#pragma unroll
      for (int off = 1; off < 16; off <<= 1) {
        tp0 += __shfl_xor(tp0, off, 64);
        tp1 += __shfl_xor(tp1, off, 64);
      }
      if (c15 == 0) {
        atomicAdd(&tws[(rowg << 1)], tp0);
        atomicAdd(&tws[(rowg << 1) + 1], tp1);
      }
    }
  }
}

// ------------- K2: a||b GEMM + tanh/sigmoid + (a*b)@Wa^T partial -> atomic A
// 128 rows x 256 out-cols, 4 waves of 32x256.  DOUBLE-BUFFERED like K1.
// LDS = 2*(16+32) = 96KB -> 1 block/CU.  8 K-steps (L=512, BK=64).
__global__ __launch_bounds__(256) void k2_gemm2(const unsigned short* __restrict__ hB,
                                                const unsigned short* __restrict__ W2B,
                                                const float* __restrict__ bv,
                                                const float* __restrict__ bu,
                                                const float* __restrict__ Wa,
                                                float* __restrict__ Aws) {
  __shared__ __align__(16) unsigned short hs[2][128 * 64];   // 2 x 16KB
  __shared__ __align__(16) unsigned short wt[2][256 * 64];   // 2 x 32KB
  const int tid = threadIdx.x, lane = tid & 63, wv = tid >> 6;
  const int cbk = blockIdx.x & 1, rbk = blockIdx.x >> 1;
  const int row0 = rbk << 7;
  const int q = lane >> 4, c15 = lane & 15;

  f32x4 acc[2][16];
#pragma unroll
  for (int i = 0; i < 2; ++i)
#pragma unroll
    for (int j = 0; j < 16; ++j) acc[i][j] = {0.f, 0.f, 0.f, 0.f};

#define K2_STAGE(B, KK)                                                         \
  {                                                                             \
    _Pragma("unroll")                                                           \
    for (int i = 0; i < 4; ++i) {                                               \
      const int g = (wv << 2) + i;                                              \
      const int slot = (g << 6) + lane;                                         \
      const int j = slot >> 3;                                                  \
      const int s = slot & 7;                                                   \
      const int k8 = s ^ (j & 7);                                               \
      GLDS16(hB + (size_t)(row0 + j) * L + (KK) + (k8 << 3), &hs[B][g << 9]);   \
    }                                                                           \
    _Pragma("unroll")                                                           \
    for (int i = 0; i < 8; ++i) {                                               \
      const int g = (wv << 3) + i;                                              \
      const int slot = (g << 6) + lane;                                         \
      const int j = slot >> 3;                                                  \
      const int s = slot & 7;                                                   \
      const int k8 = s ^ (j & 7);                                               \
      const int w2row = (j < 128) ? ((cbk << 7) + j) : (DD + (cbk << 7) + (j - 128)); \
      GLDS16(W2B + (size_t)w2row * L + (KK) + (k8 << 3), &wt[B][g << 9]);       \
    }                                                                           \
  }

  K2_STAGE(0, 0);
  __syncthreads();

  for (int t = 0; t < 8; ++t) {
    const int cur = t & 1;
    if (t < 7) K2_STAGE(cur ^ 1, (t + 1) << 6);
    const unsigned short* hsb = hs[cur];
    const unsigned short* wtb = wt[cur];
#pragma unroll
    for (int ks = 0; ks < 2; ++ks) {
      const int ch = (ks << 2) + q;
      bf16x8 af[2];
#pragma unroll
      for (int mt = 0; mt < 2; ++mt) {
        const int rr = (wv << 5) + (mt << 4) + c15;
        af[mt] = *(const bf16x8*)(hsb + (rr << 6) + ((ch ^ (rr & 7)) << 3));
      }
#pragma unroll
      for (int nt = 0; nt < 16; ++nt) {
        const int jj = (nt << 4) + c15;
        const bf16x8 bb = *(const bf16x8*)(wtb + (jj << 6) + ((ch ^ (jj & 7)) << 3));
        acc[0][nt] = __builtin_amdgcn_mfma_f32_16x16x32_bf16(af[0], bb, acc[0][nt], 0, 0, 0);
        acc[1][nt] = __builtin_amdgcn_mfma_f32_16x16x32_bf16(af[1], bb, acc[1][nt], 0, 0, 0);
      }
    }
    __syncthreads();
  }
  // epilogue
  float wa0[8], wa1[8], bvv[8], buv[8];
#pragma unroll
  for (int nt = 0; nt < 8; ++nt) {
    const int d = (cbk << 7) + (nt << 4) + c15;
    wa0[nt] = Wa[d]; wa1[nt] = Wa[DD + d];
    bvv[nt] = bv[d]; buv[nt] = bu[d];
  }
#pragma unroll
  for (int mt = 0; mt < 2; ++mt) {
#pragma unroll
    for (int r = 0; r < 4; ++r) {
      const int rowg = row0 + (wv << 5) + (mt << 4) + (q << 2) + r;
      float p0 = 0.f, p1 = 0.f;
#pragma unroll
      for (int nt = 0; nt < 8; ++nt) {
        const float av = ftanh(acc[mt][nt][r] + bvv[nt]);
        const float bx = fsig(acc[mt][nt + 8][r] + buv[nt]);
        const float ab = av * bx;
        p0 += ab * wa0[nt];
        p1 += ab * wa1[nt];
      }
#pragma unroll
      for (int off = 1; off < 16; off <<= 1) {
        p0 += __shfl_xor(p0, off, 64);
        p1 += __shfl_xor(p1, off, 64);
      }
      if (c15 == 0) {
        atomicAdd(&Aws[(rowg << 1)], p0);
        atomicAdd(&Aws[(rowg << 1) + 1], p1);
      }
    }
  }
}

// ------ K3a: elementwise: A=Aws+ba -> out, exp-sums z/s, key min/max
__global__ void k3a_elem(const float* __restrict__ Aws, const float* __restrict__ tws,
                         const float* __restrict__ ba, const int* __restrict__ lblp,
                         float* __restrict__ out,
                         float* __restrict__ scalF, unsigned* __restrict__ scalU) {
  const int row = blockIdx.x * 256 + threadIdx.x;
  const int lane = threadIdx.x & 63;
  const float2 Ap = ((const float2*)Aws)[row];
  const float2 tp = ((const float2*)tws)[row];
  const float A0 = Ap.x + ba[0];
  const float A1 = Ap.y + ba[1];
  out[4 + row] = A0;
  out[4 + NROWS + row] = A1;
  const float e0 = __expf(A0), e1 = __expf(A1);
  float z0 = e0, z1 = e1, s0 = e0 * tp.x, s1 = e1 * tp.y;
  const int lbl = *lblp;
  unsigned u = encf(lbl ? A1 : A0);
  unsigned umin = u, umax = u;
#pragma unroll
  for (int off = 1; off < 64; off <<= 1) {
    z0 += __shfl_xor(z0, off, 64);
    z1 += __shfl_xor(z1, off, 64);
    s0 += __shfl_xor(s0, off, 64);
    s1 += __shfl_xor(s1, off, 64);
    const unsigned om = (unsigned)__shfl_xor((int)umin, off, 64);
    const unsigned oM = (unsigned)__shfl_xor((int)umax, off, 64);
    umin = umin < om ? umin : om;
    umax = umax > oM ? umax : oM;
  }
  if (lane == 0) {
    atomicAdd(&scalF[0], z0); atomicAdd(&scalF[1], z1);
    atomicAdd(&scalF[2], s0); atomicAdd(&scalF[3], s1);
    atomicMin(&scalU[0], umin);
    atomicMax(&scalU[1], umax);
  }
}

// ------ K3b: linear-bin histogram with per-block LDS pre-aggregation
__global__ __launch_bounds__(1024) void k3b_hist(const float* __restrict__ out,
                                                 const int* __restrict__ lblp,
                                                 const unsigned* __restrict__ scalU,
                                                 unsigned* __restrict__ hist) {
  __shared__ unsigned lh[NBINS];
  const int tid = threadIdx.x;
  for (int i = tid; i < NBINS; i += 1024) lh[i] = 0u;
  __syncthreads();
  const int lbl = *lblp;
  const int row = blockIdx.x * 1024 + tid;
  const float A = out[4 + (size_t)lbl * NROWS + row];
  const float mn = decf(scalU[0]);
  const float mx = decf(scalU[1]);
  const float scale = (mx > mn) ? (float)(NBINS - 1) / (mx - mn) : 0.f;
  int bin = (int)((A - mn) * scale);
  bin = bin < 0 ? 0 : (bin > NBINS - 1 ? NBINS - 1 : bin);
  atomicAdd(&lh[bin], 1u);
  __syncthreads();
  for (int i = tid; i < NBINS; i += 1024) {
    const unsigned c = lh[i];
    if (c) atomicAdd(&hist[i], c);
  }
}

// -------- K4: hist scan -> threshold bins; bag logits + y_proba -> out[0..3]
__global__ void k4_scan(const unsigned* __restrict__ hist,
                        const float* __restrict__ scalF,
                        unsigned* __restrict__ scalU,
                        const float* __restrict__ bbag,
                        float* __restrict__ out) {
  __shared__ unsigned csum[256];
  const int t = threadIdx.x;
  unsigned s = 0;
  for (int b = 0; b < 64; ++b) s += hist[t * 64 + b];
  csum[t] = s;
  __syncthreads();
  if (t == 0) {
    unsigned acc = 0; int ch = 255;
    for (; ch > 0; --ch) { if (acc + csum[ch] >= NI) break; acc += csum[ch]; }
    unsigned binHi = 0;
    for (int b = ch * 64 + 63; b >= ch * 64; --b) { acc += hist[b]; if (acc >= NI) { binHi = (unsigned)b; break; } }
    scalU[6] = binHi;
    acc = 0; int cl = 0;
    for (; cl < 255; ++cl) { if (acc + csum[cl] >= NI) break; acc += csum[cl]; }
    unsigned binLo = NBINS - 1;
    for (int b = cl * 64; b < cl * 64 + 64; ++b) { acc += hist[b]; if (acc >= NI) { binLo = (unsigned)b; break; } }
    scalU[7] = binLo;
    const float l0 = scalF[2] / scalF[0] + bbag[0];
    const float l1 = scalF[3] / scalF[1] + bbag[1];
    const float m = fmaxf(l0, l1);
    const float e0 = __expf(l0 - m), e1 = __expf(l1 - m);
    const float inv = 1.0f / (e0 + e1);
    out[0] = l0; out[1] = l1; out[2] = e0 * inv; out[3] = e1 * inv;
  }
}

// ----------------------------- K5: collect top/bottom candidates by bin
__global__ void k5_collect(const float* __restrict__ out,
                           const int* __restrict__ lblp,
                           unsigned* __restrict__ scalU,
                           unsigned* __restrict__ chK, unsigned* __restrict__ chI,
                           unsigned* __restrict__ clK, unsigned* __restrict__ clI) {
  const int binHi = (int)scalU[6], binLo = (int)scalU[7];
  const float mn = decf(scalU[0]);
  const float mx = decf(scalU[1]);
  const float scale = (mx > mn) ? (float)(NBINS - 1) / (mx - mn) : 0.f;
  const int lbl = *lblp;
  const float* Ap = out + 4 + (size_t)lbl * NROWS;
  const int n = blockIdx.x * 256 + threadIdx.x;
  const float A = Ap[n];
  int bin = (int)((A - mn) * scale);
  bin = bin < 0 ? 0 : (bin > NBINS - 1 ? NBINS - 1 : bin);
  const unsigned u = encf(A);
  if (bin >= binHi) { unsigned p = atomicAdd(&scalU[4], 1u); if (p < CAP) { chK[p] = u; chI[p] = (unsigned)n; } }
  if (bin <= binLo) { unsigned p = atomicAdd(&scalU[5], 1u); if (p < CAP) { clK[p] = u; clI[p] = (unsigned)n; } }
}

// -------- K6: exact rank selection + instance logits + SmoothTop1SVM loss
__global__ __launch_bounds__(256) void k6_loss(const unsigned* __restrict__ scalU,
                                               const unsigned* __restrict__ chK, const unsigned* __restrict__ chI,
                                               const unsigned* __restrict__ clK, const unsigned* __restrict__ clI,
                                               const unsigned short* __restrict__ hB,
                                               const float* __restrict__ Winst,
                                               const float* __restrict__ binst,
                                               const int* __restrict__ lblp,
                                               float* __restrict__ out) {
  __shared__ unsigned kH[CAP], iH[CAP], kL[CAP], iL[CAP];
  __shared__ int selT[NI], selB[NI];
  __shared__ float lossA[256];
  const int t = threadIdx.x;
  const int lbl = *lblp;
  const unsigned cH = scalU[4], cL = scalU[5];
  const int nH = (int)(cH < CAP ? cH : CAP);
  const int nL = (int)(cL < CAP ? cL : CAP);
  if (t < NI) { selT[t] = 0; selB[t] = 0; }
  for (int i = t; i < nH; i += 256) { kH[i] = chK[i]; iH[i] = chI[i]; }
  for (int i = t; i < nL; i += 256) { kL[i] = clK[i]; iL[i] = clI[i]; }
  __syncthreads();
  for (int c = t; c < nH; c += 256) {
    const unsigned k = kH[c], id = iH[c];
    int rank = 0;
    for (int j = 0; j < nH; ++j) rank += (kH[j] > k) || (kH[j] == k && iH[j] < id);
    if (rank < NI) selT[rank] = (int)id;
  }
  for (int c = t; c < nL; c += 256) {
    const unsigned k = kL[c], id = iL[c];
    int rank = 0;
    for (int j = 0; j < nL; ++j) rank += (kL[j] < k) || (kL[j] == k && iL[j] < id);
    if (rank < NI) selB[rank] = (int)id;
  }
  __syncthreads();
  float loss = 0.f;
  if (t < 2 * NI) {
    const int idx = (t < NI) ? selT[t] : selB[t - NI];
    const int target = (t < NI) ? 1 : 0;
    const unsigned short* hp = hB + (size_t)idx * L;
    const float* w0 = Winst + (size_t)lbl * 2 * L;
    const float* w1 = w0 + L;
    float l0 = binst[lbl * 2 + 0], l1 = binst[lbl * 2 + 1];
    for (int k = 0; k < L; ++k) {
      const float hv = bf2f(hp[k]);
      l0 += hv * w0[k];
      l1 += hv * w1[k];
    }
    const float z0 = l0 + (target ? 1.0f : 0.0f);
    const float z1 = l1 + (target ? 0.0f : 1.0f);
    const float m = fmaxf(z0, z1);
    const float lse = m + logf(__expf(z0 - m) + __expf(z1 - m));
    loss = lse - (target ? l1 : l0);
  }
  lossA[t] = loss;
  __syncthreads();
  for (int sft = 128; sft; sft >>= 1) {
    if (t < sft) lossA[t] += lossA[t + sft];
    __syncthreads();
  }
  if (t == 0) out[4 + 2 * NROWS] = lossA[0] / 100.0f;
}

extern "C" void kernel_launch(void* const* d_in, const int* in_sizes, int n_in,
                              void* d_out, int out_size, void* d_ws, size_t ws_size,
                              hipStream_t stream) {
  const float* x     = (const float*)d_in[0];
  const int*   lbl   = (const int*)d_in[1];
  const float* Wc    = (const float*)d_in[2];
  const float* bc    = (const float*)d_in[3];
  const float* Wv    = (const float*)d_in[4];
  const float* bv    = (const float*)d_in[5];
  const float* Wu    = (const float*)d_in[6];
  const float* bu    = (const float*)d_in[7];
  const float* Wa    = (const float*)d_in[8];
  const float* ba    = (const float*)d_in[9];
  const float* Winst = (const float*)d_in[10];
  const float* binst = (const float*)d_in[11];
  const float* Wbag  = (const float*)d_in[12];
  const float* bbag  = (const float*)d_in[13];
  float* out = (float*)d_out;
  char* ws = (char*)d_ws;

  unsigned short* hB   = (unsigned short*)(ws);                  // 134217728 B
  unsigned short* WcB  = (unsigned short*)(ws + 134217728LL);    // 1048576 B
  unsigned short* W2B  = (unsigned short*)(ws + 135266304LL);    // 524288 B
  float*          Aws  = (float*)(ws + 135790592LL);             // 1048576 B
  float*          tws  = (float*)(ws + 136839168LL);             // 1048576 B
  unsigned*       hist = (unsigned*)(ws + 137887744LL);          // 65536 B
  float*          scalF= (float*)(ws + 137953280LL);             // 64 B
  unsigned*       scalU= (unsigned*)(ws + 137953344LL);          // 64 B
  unsigned*       chK  = (unsigned*)(ws + 137953408LL);          // 4*CAP*4 B
  unsigned*       chI  = chK + CAP;
  unsigned*       clK  = chI + CAP;
  unsigned*       clI  = clK + CAP;

  k0_init<<<2048, 256, 0, stream>>>(Wc, Wv, Wu, WcB, W2B, Aws, tws, hist, scalF, scalU);
  k1_gemm1<<<2048, 256, 0, stream>>>(x, WcB, bc, Wbag, hB, tws);
  k2_gemm2<<<2048, 256, 0, stream>>>(hB, W2B, bv, bu, Wa, Aws);
  k3a_elem<<<512, 256, 0, stream>>>(Aws, tws, ba, lbl, out, scalF, scalU);
  k3b_hist<<<128, 1024, 0, stream>>>(out, lbl, scalU, hist);
  k4_scan<<<1, 256, 0, stream>>>(hist, scalF, scalU, bbag, out);
  k5_collect<<<512, 256, 0, stream>>>(out, lbl, scalU, chK, chI, clK, clI);
  k6_loss<<<1, 256, 0, stream>>>(scalU, chK, chI, clK, clI, hB, Winst, binst, lbl, out);
}

// Round 5
// 1273.072 us; speedup vs baseline: 1.0295x; 1.0295x over previous
//
#include <hip/hip_runtime.h>
#include <hip/hip_bf16.h>
#include <math.h>

#define NROWS 131072
#define E 1024
#define L 512
#define DD 256
#define NI 50
#define CAP 2048
#define NBINS 16384

typedef __attribute__((ext_vector_type(8))) short bf16x8;
typedef __attribute__((ext_vector_type(4))) float f32x4;

__device__ __forceinline__ unsigned short f2bf(float f) {
  unsigned u = __float_as_uint(f);
  unsigned r = (u + 0x7FFFu + ((u >> 16) & 1u)) >> 16;   // RNE
  return (unsigned short)r;
}
__device__ __forceinline__ float bf2f(unsigned short b) {
  return __uint_as_float(((unsigned)b) << 16);
}
__device__ __forceinline__ float frcp(float x) { return __builtin_amdgcn_rcpf(x); }
__device__ __forceinline__ float fsig(float x) { return frcp(1.0f + __expf(-x)); }
__device__ __forceinline__ float ftanh(float x) { return 2.0f * frcp(1.0f + __expf(-2.0f * x)) - 1.0f; }
__device__ __forceinline__ unsigned encf(float f) {
  unsigned u = __float_as_uint(f);
  return (u & 0x80000000u) ? ~u : (u | 0x80000000u);
}
__device__ __forceinline__ float decf(unsigned e) {
  unsigned b = (e & 0x80000000u) ? (e & 0x7FFFFFFFu) : ~e;
  return __uint_as_float(b);
}
// packed fp32x2 -> bf16x2 (RNE), low short = first operand
__device__ __forceinline__ unsigned cvtpk(float a, float b) {
  unsigned r;
  asm("v_cvt_pk_bf16_f32 %0, %1, %2" : "=v"(r) : "v"(a), "v"(b));
  return r;
}

#define GLDS16(gp, lp)                                                        \
  __builtin_amdgcn_global_load_lds(                                           \
      (const __attribute__((address_space(1))) void*)(gp),                    \
      (__attribute__((address_space(3))) void*)(lp), 16, 0, 0)

#define SBAR() __builtin_amdgcn_s_barrier()
#define SCHED0() __builtin_amdgcn_sched_barrier(0)

// ---------------------------------------------------------------- K0: init
__global__ void k0_init(const float* __restrict__ Wc, const float* __restrict__ Wv,
                        const float* __restrict__ Wu,
                        unsigned short* __restrict__ WcB, unsigned short* __restrict__ W2B,
                        float* __restrict__ Aws, float* __restrict__ tws,
                        unsigned* __restrict__ hist,
                        float* __restrict__ scalF, unsigned* __restrict__ scalU) {
  const int i0 = blockIdx.x * blockDim.x + threadIdx.x;
  const int str = gridDim.x * blockDim.x;
  if (i0 < 4) scalF[i0] = 0.f;
  if (i0 < 16) scalU[i0] = (i0 == 0) ? 0xFFFFFFFFu : 0u;
  for (int k = i0; k < NBINS; k += str) hist[k] = 0u;
  for (int k = i0; k < NROWS * 2; k += str) { Aws[k] = 0.f; tws[k] = 0.f; }
  for (int k = i0; k < L * E; k += str) WcB[k] = f2bf(Wc[k]);
  for (int k = i0; k < DD * L; k += str) { W2B[k] = f2bf(Wv[k]); W2B[DD * L + k] = f2bf(Wu[k]); }
}

// ------------- K1: h = relu(x @ Wc^T + bc); also t = h @ Wbag^T (partial, atomic)
// 128 rows x 256 cols, BK=64 (16 K-steps), 4 waves (2x2 of 64x128).
// Double-buffered with COUNTED vmcnt + raw s_barrier (T4): tile t+1 loads stay in
// flight across the compute of tile t; vmcnt never drains to 0 in the main loop.
// x staged fp32 (16-slot swizzle), wt bf16 (8-slot). LDS = 128KB.
__global__ __launch_bounds__(256) void k1_gemm1(const float* __restrict__ x,
                                                const unsigned short* __restrict__ WcB,
                                                const float* __restrict__ bc,
                                                const float* __restrict__ Wbag,
                                                unsigned short* __restrict__ hB,
                                                float* __restrict__ tws) {
  __shared__ __align__(16) float xs[2][128 * 64];            // 2 x 32KB fp32
  __shared__ __align__(16) unsigned short wt[2][256 * 64];   // 2 x 32KB bf16
  const int tid = threadIdx.x;
  const int lane = tid & 63;
  const int wv = tid >> 6;
  const int cbk = blockIdx.x & 1;
  const int rbk = blockIdx.x >> 1;
  const int row0 = rbk << 7;
  const int col0 = cbk << 8;
  const int wr = wv >> 1, wc = wv & 1;
  const int q = lane >> 4, c15 = lane & 15;

  f32x4 acc[4][8];
#pragma unroll
  for (int i = 0; i < 4; ++i)
#pragma unroll
    for (int j = 0; j < 8; ++j) acc[i][j] = {0.f, 0.f, 0.f, 0.f};

  // 16 GLDS16 per wave per tile (8 x-loads + 8 wt-loads)
#define K1_STAGE(B, KK)                                                        \
  {                                                                            \
    _Pragma("unroll")                                                          \
    for (int i = 0; i < 8; ++i) {                                              \
      const int g = (wv << 3) + i;                                             \
      const int j = (g << 2) + (lane >> 4);                                    \
      const int s = lane & 15;                                                 \
      const int s4 = (s ^ (j & 15)) << 2;                                      \
      GLDS16(x + (size_t)(row0 + j) * E + (KK) + s4, &xs[B][g << 8]);          \
    }                                                                          \
    _Pragma("unroll")                                                          \
    for (int i = 0; i < 8; ++i) {                                              \
      const int g = (wv << 3) + i;                                             \
      const int slot = (g << 6) + lane;                                        \
      const int j = slot >> 3;                                                 \
      const int s = slot & 7;                                                  \
      const int k8 = s ^ (j & 7);                                              \
      GLDS16(WcB + (size_t)(col0 + j) * E + (KK) + (k8 << 3), &wt[B][g << 9]); \
    }                                                                          \
  }

  K1_STAGE(0, 0);
  K1_STAGE(1, 64);

  for (int t = 0; t < 16; ++t) {
    const int cur = t & 1;
    // own tile-t loads complete (tile t+1's 16 may remain in flight)
    if (t < 15) {
      asm volatile("s_waitcnt vmcnt(16)" ::: "memory");
    } else {
      asm volatile("s_waitcnt vmcnt(0)" ::: "memory");
    }
    SCHED0();
    SBAR();                      // all waves' tile-t loads landed
    SCHED0();
    const float* xsb = xs[cur];
    const unsigned short* wtb = wt[cur];
#pragma unroll
    for (int ks = 0; ks < 2; ++ks) {
      const int ch = (ks << 2) + q;                      // k-chunk 0..7 (8 f32 each)
      union { bf16x8 v; unsigned u[4]; } af[4];
#pragma unroll
      for (int mt = 0; mt < 4; ++mt) {
        const int rr = (wr << 6) + (mt << 4) + c15;
        const int r15 = rr & 15;
        const f32x4 lo = *(const f32x4*)(xsb + (rr << 6) + ((((ch << 1)    ) ^ r15) << 2));
        const f32x4 hi = *(const f32x4*)(xsb + (rr << 6) + ((((ch << 1) | 1) ^ r15) << 2));
        af[mt].u[0] = cvtpk(lo[0], lo[1]);
        af[mt].u[1] = cvtpk(lo[2], lo[3]);
        af[mt].u[2] = cvtpk(hi[0], hi[1]);
        af[mt].u[3] = cvtpk(hi[2], hi[3]);
      }
#pragma unroll
      for (int nt = 0; nt < 8; ++nt) {
        const int jj = (wc << 7) + (nt << 4) + c15;
        const bf16x8 bb = *(const bf16x8*)(wtb + (jj << 6) + ((ch ^ (jj & 7)) << 3));
#pragma unroll
        for (int mt = 0; mt < 4; ++mt)
          acc[mt][nt] = __builtin_amdgcn_mfma_f32_16x16x32_bf16(af[mt].v, bb, acc[mt][nt], 0, 0, 0);
      }
    }
    SCHED0();
    SBAR();                      // all waves done reading buf[cur]
    SCHED0();
    if (t < 14) K1_STAGE(cur, (t + 2) << 6);   // refill buf[cur] for tile t+2
  }
  // epilogue: bias+relu, bag-dot partial, bf16 pack-pairs + dword stores
  float bias[8], wb0[8], wb1[8];
#pragma unroll
  for (int nt = 0; nt < 8; ++nt) {
    const int colg = col0 + (wc << 7) + (nt << 4) + c15;
    bias[nt] = bc[colg];
    wb0[nt] = Wbag[colg];
    wb1[nt] = Wbag[L + colg];
  }
#pragma unroll
  for (int mt = 0; mt < 4; ++mt) {
#pragma unroll
    for (int r = 0; r < 4; ++r) {
      const int rowg = row0 + (wr << 6) + (mt << 4) + (q << 2) + r;
      float tp0 = 0.f, tp1 = 0.f;
#pragma unroll
      for (int nt = 0; nt < 8; ++nt) {
        const int colg = col0 + (wc << 7) + (nt << 4) + c15;
        float v = acc[mt][nt][r] + bias[nt];
        v = v > 0.f ? v : 0.f;
        tp0 += v * wb0[nt];
        tp1 += v * wb1[nt];
        const unsigned short hb = f2bf(v);
        const unsigned short ob = (unsigned short)__shfl_xor((int)hb, 1, 64);
        if (!(lane & 1)) {
          *(unsigned*)(hB + (size_t)rowg * L + colg) = (unsigned)hb | ((unsigned)ob << 16);
        }
      }
#pragma unroll
      for (int off = 1; off < 16; off <<= 1) {
        tp0 += __shfl_xor(tp0, off, 64);
        tp1 += __shfl_xor(tp1, off, 64);
      }
      if (c15 == 0) {
        atomicAdd(&tws[(rowg << 1)], tp0);
        atomicAdd(&tws[(rowg << 1) + 1], tp1);
      }
    }
  }
}

// ------------- K2: a||b GEMM + tanh/sigmoid + (a*b)@Wa^T partial -> atomic A
// 128 rows x 256 out-cols, 4 waves of 32x256.  Double-buffered, counted vmcnt (12
// loads/wave/tile).  LDS = 96KB.  8 K-steps (L=512, BK=64).
__global__ __launch_bounds__(256) void k2_gemm2(const unsigned short* __restrict__ hB,
                                                const unsigned short* __restrict__ W2B,
                                                const float* __restrict__ bv,
                                                const float* __restrict__ bu,
                                                const float* __restrict__ Wa,
                                                float* __restrict__ Aws) {
  __shared__ __align__(16) unsigned short hs[2][128 * 64];   // 2 x 16KB
  __shared__ __align__(16) unsigned short wt[2][256 * 64];   // 2 x 32KB
  const int tid = threadIdx.x, lane = tid & 63, wv = tid >> 6;
  const int cbk = blockIdx.x & 1, rbk = blockIdx.x >> 1;
  const int row0 = rbk << 7;
  const int q = lane >> 4, c15 = lane & 15;

  f32x4 acc[2][16];
#pragma unroll
  for (int i = 0; i < 2; ++i)
#pragma unroll
    for (int j = 0; j < 16; ++j) acc[i][j] = {0.f, 0.f, 0.f, 0.f};

#define K2_STAGE(B, KK)                                                         \
  {                                                                             \
    _Pragma("unroll")                                                           \
    for (int i = 0; i < 4; ++i) {                                               \
      const int g = (wv << 2) + i;                                              \
      const int slot = (g << 6) + lane;                                         \
      const int j = slot >> 3;                                                  \
      const int s = slot & 7;                                                   \
      const int k8 = s ^ (j & 7);                                               \
      GLDS16(hB + (size_t)(row0 + j) * L + (KK) + (k8 << 3), &hs[B][g << 9]);   \
    }                                                                           \
    _Pragma("unroll")                                                           \
    for (int i = 0; i < 8; ++i) {                                               \
      const int g = (wv << 3) + i;                                              \
      const int slot = (g << 6) + lane;                                         \
      const int j = slot >> 3;                                                  \
      const int s = slot & 7;                                                   \
      const int k8 = s ^ (j & 7);                                               \
      const int w2row = (j < 128) ? ((cbk << 7) + j) : (DD + (cbk << 7) + (j - 128)); \
      GLDS16(W2B + (size_t)w2row * L + (KK) + (k8 << 3), &wt[B][g << 9]);       \
    }                                                                           \
  }

  K2_STAGE(0, 0);
  K2_STAGE(1, 64);

  for (int t = 0; t < 8; ++t) {
    const int cur = t & 1;
    if (t < 7) {
      asm volatile("s_waitcnt vmcnt(12)" ::: "memory");
    } else {
      asm volatile("s_waitcnt vmcnt(0)" ::: "memory");
    }
    SCHED0();
    SBAR();
    SCHED0();
    const unsigned short* hsb = hs[cur];
    const unsigned short* wtb = wt[cur];
#pragma unroll
    for (int ks = 0; ks < 2; ++ks) {
      const int ch = (ks << 2) + q;
      bf16x8 af[2];
#pragma unroll
      for (int mt = 0; mt < 2; ++mt) {
        const int rr = (wv << 5) + (mt << 4) + c15;
        af[mt] = *(const bf16x8*)(hsb + (rr << 6) + ((ch ^ (rr & 7)) << 3));
      }
#pragma unroll
      for (int nt = 0; nt < 16; ++nt) {
        const int jj = (nt << 4) + c15;
        const bf16x8 bb = *(const bf16x8*)(wtb + (jj << 6) + ((ch ^ (jj & 7)) << 3));
        acc[0][nt] = __builtin_amdgcn_mfma_f32_16x16x32_bf16(af[0], bb, acc[0][nt], 0, 0, 0);
        acc[1][nt] = __builtin_amdgcn_mfma_f32_16x16x32_bf16(af[1], bb, acc[1][nt], 0, 0, 0);
      }
    }
    SCHED0();
    SBAR();
    SCHED0();
    if (t < 6) K2_STAGE(cur, (t + 2) << 6);
  }
  // epilogue
  float wa0[8], wa1[8], bvv[8], buv[8];
#pragma unroll
  for (int nt = 0; nt < 8; ++nt) {
    const int d = (cbk << 7) + (nt << 4) + c15;
    wa0[nt] = Wa[d]; wa1[nt] = Wa[DD + d];
    bvv[nt] = bv[d]; buv[nt] = bu[d];
  }
#pragma unroll
  for (int mt = 0; mt < 2; ++mt) {
#pragma unroll
    for (int r = 0; r < 4; ++r) {
      const int rowg = row0 + (wv << 5) + (mt << 4) + (q << 2) + r;
      float p0 = 0.f, p1 = 0.f;
#pragma unroll
      for (int nt = 0; nt < 8; ++nt) {
        const float av = ftanh(acc[mt][nt][r] + bvv[nt]);
        const float bx = fsig(acc[mt][nt + 8][r] + buv[nt]);
        const float ab = av * bx;
        p0 += ab * wa0[nt];
        p1 += ab * wa1[nt];
      }
#pragma unroll
      for (int off = 1; off < 16; off <<= 1) {
        p0 += __shfl_xor(p0, off, 64);
        p1 += __shfl_xor(p1, off, 64);
      }
      if (c15 == 0) {
        atomicAdd(&Aws[(rowg << 1)], p0);
        atomicAdd(&Aws[(rowg << 1) + 1], p1);
      }
    }
  }
}

// ------ K3a: elementwise: A=Aws+ba -> out, exp-sums z/s, key min/max
__global__ void k3a_elem(const float* __restrict__ Aws, const float* __restrict__ tws,
                         const float* __restrict__ ba, const int* __restrict__ lblp,
                         float* __restrict__ out,
                         float* __restrict__ scalF, unsigned* __restrict__ scalU) {
  const int row = blockIdx.x * 256 + threadIdx.x;
  const int lane = threadIdx.x & 63;
  const float2 Ap = ((const float2*)Aws)[row];
  const float2 tp = ((const float2*)tws)[row];
  const float A0 = Ap.x + ba[0];
  const float A1 = Ap.y + ba[1];
  out[4 + row] = A0;
  out[4 + NROWS + row] = A1;
  const float e0 = __expf(A0), e1 = __expf(A1);
  float z0 = e0, z1 = e1, s0 = e0 * tp.x, s1 = e1 * tp.y;
  const int lbl = *lblp;
  unsigned u = encf(lbl ? A1 : A0);
  unsigned umin = u, umax = u;
#pragma unroll
  for (int off = 1; off < 64; off <<= 1) {
    z0 += __shfl_xor(z0, off, 64);
    z1 += __shfl_xor(z1, off, 64);
    s0 += __shfl_xor(s0, off, 64);
    s1 += __shfl_xor(s1, off, 64);
    const unsigned om = (unsigned)__shfl_xor((int)umin, off, 64);
    const unsigned oM = (unsigned)__shfl_xor((int)umax, off, 64);
    umin = umin < om ? umin : om;
    umax = umax > oM ? umax : oM;
  }
  if (lane == 0) {
    atomicAdd(&scalF[0], z0); atomicAdd(&scalF[1], z1);
    atomicAdd(&scalF[2], s0); atomicAdd(&scalF[3], s1);
    atomicMin(&scalU[0], umin);
    atomicMax(&scalU[1], umax);
  }
}

// ------ K3b: linear-bin histogram with per-block LDS pre-aggregation
__global__ __launch_bounds__(1024) void k3b_hist(const float* __restrict__ out,
                                                 const int* __restrict__ lblp,
                                                 const unsigned* __restrict__ scalU,
                                                 unsigned* __restrict__ hist) {
  __shared__ unsigned lh[NBINS];
  const int tid = threadIdx.x;
  for (int i = tid; i < NBINS; i += 1024) lh[i] = 0u;
  __syncthreads();
  const int lbl = *lblp;
  const int row = blockIdx.x * 1024 + tid;
  const float A = out[4 + (size_t)lbl * NROWS + row];
  const float mn = decf(scalU[0]);
  const float mx = decf(scalU[1]);
  const float scale = (mx > mn) ? (float)(NBINS - 1) / (mx - mn) : 0.f;
  int bin = (int)((A - mn) * scale);
  bin = bin < 0 ? 0 : (bin > NBINS - 1 ? NBINS - 1 : bin);
  atomicAdd(&lh[bin], 1u);
  __syncthreads();
  for (int i = tid; i < NBINS; i += 1024) {
    const unsigned c = lh[i];
    if (c) atomicAdd(&hist[i], c);
  }
}

// -------- K4: hist scan -> threshold bins; bag logits + y_proba -> out[0..3]
__global__ void k4_scan(const unsigned* __restrict__ hist,
                        const float* __restrict__ scalF,
                        unsigned* __restrict__ scalU,
                        const float* __restrict__ bbag,
                        float* __restrict__ out) {
  __shared__ unsigned csum[256];
  const int t = threadIdx.x;
  unsigned s = 0;
  for (int b = 0; b < 64; ++b) s += hist[t * 64 + b];
  csum[t] = s;
  __syncthreads();
  if (t == 0) {
    unsigned acc = 0; int ch = 255;
    for (; ch > 0; --ch) { if (acc + csum[ch] >= NI) break; acc += csum[ch]; }
    unsigned binHi = 0;
    for (int b = ch * 64 + 63; b >= ch * 64; --b) { acc += hist[b]; if (acc >= NI) { binHi = (unsigned)b; break; } }
    scalU[6] = binHi;
    acc = 0; int cl = 0;
    for (; cl < 255; ++cl) { if (acc + csum[cl] >= NI) break; acc += csum[cl]; }
    unsigned binLo = NBINS - 1;
    for (int b = cl * 64; b < cl * 64 + 64; ++b) { acc += hist[b]; if (acc >= NI) { binLo = (unsigned)b; break; } }
    scalU[7] = binLo;
    const float l0 = scalF[2] / scalF[0] + bbag[0];
    const float l1 = scalF[3] / scalF[1] + bbag[1];
    const float m = fmaxf(l0, l1);
    const float e0 = __expf(l0 - m), e1 = __expf(l1 - m);
    const float inv = 1.0f / (e0 + e1);
    out[0] = l0; out[1] = l1; out[2] = e0 * inv; out[3] = e1 * inv;
  }
}

// ----------------------------- K5: collect top/bottom candidates by bin
__global__ void k5_collect(const float* __restrict__ out,
                           const int* __restrict__ lblp,
                           unsigned* __restrict__ scalU,
                           unsigned* __restrict__ chK, unsigned* __restrict__ chI,
                           unsigned* __restrict__ clK, unsigned* __restrict__ clI) {
  const int binHi = (int)scalU[6], binLo = (int)scalU[7];
  const float mn = decf(scalU[0]);
  const float mx = decf(scalU[1]);
  const float scale = (mx > mn) ? (float)(NBINS - 1) / (mx - mn) : 0.f;
  const int lbl = *lblp;
  const float* Ap = out + 4 + (size_t)lbl * NROWS;
  const int n = blockIdx.x * 256 + threadIdx.x;
  const float A = Ap[n];
  int bin = (int)((A - mn) * scale);
  bin = bin < 0 ? 0 : (bin > NBINS - 1 ? NBINS - 1 : bin);
  const unsigned u = encf(A);
  if (bin >= binHi) { unsigned p = atomicAdd(&scalU[4], 1u); if (p < CAP) { chK[p] = u; chI[p] = (unsigned)n; } }
  if (bin <= binLo) { unsigned p = atomicAdd(&scalU[5], 1u); if (p < CAP) { clK[p] = u; clI[p] = (unsigned)n; } }
}

// -------- K6: exact rank selection + instance logits + SmoothTop1SVM loss
__global__ __launch_bounds__(256) void k6_loss(const unsigned* __restrict__ scalU,
                                               const unsigned* __restrict__ chK, const unsigned* __restrict__ chI,
                                               const unsigned* __restrict__ clK, const unsigned* __restrict__ clI,
                                               const unsigned short* __restrict__ hB,
                                               const float* __restrict__ Winst,
                                               const float* __restrict__ binst,
                                               const int* __restrict__ lblp,
                                               float* __restrict__ out) {
  __shared__ unsigned kH[CAP], iH[CAP], kL[CAP], iL[CAP];
  __shared__ int selT[NI], selB[NI];
  __shared__ float lossA[256];
  const int t = threadIdx.x;
  const int lbl = *lblp;
  const unsigned cH = scalU[4], cL = scalU[5];
  const int nH = (int)(cH < CAP ? cH : CAP);
  const int nL = (int)(cL < CAP ? cL : CAP);
  if (t < NI) { selT[t] = 0; selB[t] = 0; }
  for (int i = t; i < nH; i += 256) { kH[i] = chK[i]; iH[i] = chI[i]; }
  for (int i = t; i < nL; i += 256) { kL[i] = clK[i]; iL[i] = clI[i]; }
  __syncthreads();
  for (int c = t; c < nH; c += 256) {
    const unsigned k = kH[c], id = iH[c];
    int rank = 0;
    for (int j = 0; j < nH; ++j) rank += (kH[j] > k) || (kH[j] == k && iH[j] < id);
    if (rank < NI) selT[rank] = (int)id;
  }
  for (int c = t; c < nL; c += 256) {
    const unsigned k = kL[c], id = iL[c];
    int rank = 0;
    for (int j = 0; j < nL; ++j) rank += (kL[j] < k) || (kL[j] == k && iL[j] < id);
    if (rank < NI) selB[rank] = (int)id;
  }
  __syncthreads();
  float loss = 0.f;
  if (t < 2 * NI) {
    const int idx = (t < NI) ? selT[t] : selB[t - NI];
    const int target = (t < NI) ? 1 : 0;
    const unsigned short* hp = hB + (size_t)idx * L;
    const float* w0 = Winst + (size_t)lbl * 2 * L;
    const float* w1 = w0 + L;
    float l0 = binst[lbl * 2 + 0], l1 = binst[lbl * 2 + 1];
    for (int k = 0; k < L; ++k) {
      const float hv = bf2f(hp[k]);
      l0 += hv * w0[k];
      l1 += hv * w1[k];
    }
    const float z0 = l0 + (target ? 1.0f : 0.0f);
    const float z1 = l1 + (target ? 0.0f : 1.0f);
    const float m = fmaxf(z0, z1);
    const float lse = m + logf(__expf(z0 - m) + __expf(z1 - m));
    loss = lse - (target ? l1 : l0);
  }
  lossA[t] = loss;
  __syncthreads();
  for (int sft = 128; sft; sft >>= 1) {
    if (t < sft) lossA[t] += lossA[t + sft];
    __syncthreads();
  }
  if (t == 0) out[4 + 2 * NROWS] = lossA[0] / 100.0f;
}

extern "C" void kernel_launch(void* const* d_in, const int* in_sizes, int n_in,
                              void* d_out, int out_size, void* d_ws, size_t ws_size,
                              hipStream_t stream) {
  const float* x     = (const float*)d_in[0];
  const int*   lbl   = (const int*)d_in[1];
  const float* Wc    = (const float*)d_in[2];
  const float* bc    = (const float*)d_in[3];
  const float* Wv    = (const float*)d_in[4];
  const float* bv    = (const float*)d_in[5];
  const float* Wu    = (const float*)d_in[6];
  const float* bu    = (const float*)d_in[7];
  const float* Wa    = (const float*)d_in[8];
  const float* ba    = (const float*)d_in[9];
  const float* Winst = (const float*)d_in[10];
  const float* binst = (const float*)d_in[11];
  const float* Wbag  = (const float*)d_in[12];
  const float* bbag  = (const float*)d_in[13];
  float* out = (float*)d_out;
  char* ws = (char*)d_ws;

  unsigned short* hB   = (unsigned short*)(ws);                  // 134217728 B
  unsigned short* WcB  = (unsigned short*)(ws + 134217728LL);    // 1048576 B
  unsigned short* W2B  = (unsigned short*)(ws + 135266304LL);    // 524288 B
  float*          Aws  = (float*)(ws + 135790592LL);             // 1048576 B
  float*          tws  = (float*)(ws + 136839168LL);             // 1048576 B
  unsigned*       hist = (unsigned*)(ws + 137887744LL);          // 65536 B
  float*          scalF= (float*)(ws + 137953280LL);             // 64 B
  unsigned*       scalU= (unsigned*)(ws + 137953344LL);          // 64 B
  unsigned*       chK  = (unsigned*)(ws + 137953408LL);          // 4*CAP*4 B
  unsigned*       chI  = chK + CAP;
  unsigned*       clK  = chI + CAP;
  unsigned*       clI  = clK + CAP;

  k0_init<<<2048, 256, 0, stream>>>(Wc, Wv, Wu, WcB, W2B, Aws, tws, hist, scalF, scalU);
  k1_gemm1<<<2048, 256, 0, stream>>>(x, WcB, bc, Wbag, hB, tws);
  k2_gemm2<<<2048, 256, 0, stream>>>(hB, W2B, bv, bu, Wa, Aws);
  k3a_elem<<<512, 256, 0, stream>>>(Aws, tws, ba, lbl, out, scalF, scalU);
  k3b_hist<<<128, 1024, 0, stream>>>(out, lbl, scalU, hist);
  k4_scan<<<1, 256, 0, stream>>>(hist, scalF, scalU, bbag, out);
  k5_collect<<<512, 256, 0, stream>>>(out, lbl, scalU, chK, chI, clK, clI);
  k6_loss<<<1, 256, 0, stream>>>(scalU, chK, chI, clK, clI, hB, Winst, binst, lbl, out);
}

// Round 6
// 1177.171 us; speedup vs baseline: 1.1134x; 1.0815x over previous
//
#include <hip/hip_runtime.h>
#include <hip/hip_bf16.h>
#include <math.h>

#define NROWS 131072
#define E 1024
#define L 512
#define DD 256
#define NI 50
#define CAP 2048
#define NBINS 16384

typedef __attribute__((ext_vector_type(8))) short bf16x8;
typedef __attribute__((ext_vector_type(4))) float f32x4;

__device__ __forceinline__ unsigned short f2bf(float f) {
  unsigned u = __float_as_uint(f);
  unsigned r = (u + 0x7FFFu + ((u >> 16) & 1u)) >> 16;   // RNE
  return (unsigned short)r;
}
__device__ __forceinline__ float bf2f(unsigned short b) {
  return __uint_as_float(((unsigned)b) << 16);
}
__device__ __forceinline__ float frcp(float x) { return __builtin_amdgcn_rcpf(x); }
__device__ __forceinline__ float fsig(float x) { return frcp(1.0f + __expf(-x)); }
__device__ __forceinline__ float ftanh(float x) { return 2.0f * frcp(1.0f + __expf(-2.0f * x)) - 1.0f; }
__device__ __forceinline__ unsigned encf(float f) {
  unsigned u = __float_as_uint(f);
  return (u & 0x80000000u) ? ~u : (u | 0x80000000u);
}
__device__ __forceinline__ float decf(unsigned e) {
  unsigned b = (e & 0x80000000u) ? (e & 0x7FFFFFFFu) : ~e;
  return __uint_as_float(b);
}
// packed fp32x2 -> bf16x2 (RNE), low short = first operand
__device__ __forceinline__ unsigned cvtpk(float a, float b) {
  unsigned r;
  asm("v_cvt_pk_bf16_f32 %0, %1, %2" : "=v"(r) : "v"(a), "v"(b));
  return r;
}

#define GLDS16(gp, lp)                                                        \
  __builtin_amdgcn_global_load_lds(                                           \
      (const __attribute__((address_space(1))) void*)(gp),                    \
      (__attribute__((address_space(3))) void*)(lp), 16, 0, 0)

// ---------------------------------------------------------------- K0: init
__global__ void k0_init(const float* __restrict__ Wc, const float* __restrict__ Wv,
                        const float* __restrict__ Wu,
                        unsigned short* __restrict__ WcB, unsigned short* __restrict__ W2B,
                        float* __restrict__ Aws, float* __restrict__ tws,
                        unsigned* __restrict__ hist,
                        float* __restrict__ scalF, unsigned* __restrict__ scalU) {
  const int i0 = blockIdx.x * blockDim.x + threadIdx.x;
  const int str = gridDim.x * blockDim.x;
  if (i0 < 4) scalF[i0] = 0.f;
  if (i0 < 16) scalU[i0] = (i0 == 0) ? 0xFFFFFFFFu : 0u;
  for (int k = i0; k < NBINS; k += str) hist[k] = 0u;
  for (int k = i0; k < NROWS * 2; k += str) { Aws[k] = 0.f; tws[k] = 0.f; }
  for (int k = i0; k < L * E; k += str) WcB[k] = f2bf(Wc[k]);
  for (int k = i0; k < DD * L; k += str) { W2B[k] = f2bf(Wv[k]); W2B[DD * L + k] = f2bf(Wu[k]); }
}

// ------------- K1: h = relu(x @ Wc^T + bc); also t = h @ Wbag^T (partial, atomic)
// m97-shape: 128x128 tile, 4 waves (2x2) of 64x64, BK=64, single-buffer 2-barrier loop.
// acc[4][4] = 64 VGPR -> __launch_bounds__(256,4) keeps <=128 VGPR -> 3 blocks/CU
// (LDS 48KB).  Inter-block overlap hides staging latency (m97/m114 mechanism).
// x staged fp32 async (16-slot XOR swizzle), cvtpk on fragment read; wt bf16 (8-slot).
__global__ __launch_bounds__(256, 4) void k1_gemm1(const float* __restrict__ x,
                                                   const unsigned short* __restrict__ WcB,
                                                   const float* __restrict__ bc,
                                                   const float* __restrict__ Wbag,
                                                   unsigned short* __restrict__ hB,
                                                   float* __restrict__ tws) {
  __shared__ __align__(16) float xs[128 * 64];            // 32KB fp32
  __shared__ __align__(16) unsigned short wt[128 * 64];   // 16KB bf16
  const int tid = threadIdx.x;
  const int lane = tid & 63;
  const int wv = tid >> 6;
  const int cbk = blockIdx.x & 3;          // 4 col-tiles of 128
  const int rbk = blockIdx.x >> 2;         // 1024 row-tiles
  const int row0 = rbk << 7;
  const int col0 = cbk << 7;
  const int wr = wv >> 1, wc = wv & 1;
  const int q = lane >> 4, c15 = lane & 15;

  f32x4 acc[4][4];
#pragma unroll
  for (int i = 0; i < 4; ++i)
#pragma unroll
    for (int j = 0; j < 4; ++j) acc[i][j] = {0.f, 0.f, 0.f, 0.f};

  for (int kk = 0; kk < E; kk += 64) {
    __syncthreads();
    // x tile: 128 rows x 64 f32 = 32KB, 16 slots(16B)/row, swizzle s^=(row&15)
#pragma unroll
    for (int i = 0; i < 8; ++i) {
      const int g = (wv << 3) + i;
      const int j = (g << 2) + (lane >> 4);
      const int s = lane & 15;
      const int s4 = (s ^ (j & 15)) << 2;
      GLDS16(x + (size_t)(row0 + j) * E + kk + s4, xs + (g << 8));
    }
    // weight tile: 128 cols x 64 k bf16 = 16KB, 8 slots(16B)/row, swizzle s^=(row&7)
#pragma unroll
    for (int i = 0; i < 4; ++i) {
      const int g = (wv << 2) + i;
      const int slot = (g << 6) + lane;
      const int j = slot >> 3;
      const int s = slot & 7;
      const int k8 = s ^ (j & 7);
      GLDS16(WcB + (size_t)(col0 + j) * E + kk + (k8 << 3), wt + (g << 9));
    }
    __syncthreads();
#pragma unroll
    for (int ks = 0; ks < 2; ++ks) {
      const int ch = (ks << 2) + q;                      // k-chunk 0..7 (8 f32 each)
      union { bf16x8 v; unsigned u[4]; } af[4];
#pragma unroll
      for (int mt = 0; mt < 4; ++mt) {
        const int rr = (wr << 6) + (mt << 4) + c15;
        const int r15 = rr & 15;
        const f32x4 lo = *(const f32x4*)(xs + (rr << 6) + ((((ch << 1)    ) ^ r15) << 2));
        const f32x4 hi = *(const f32x4*)(xs + (rr << 6) + ((((ch << 1) | 1) ^ r15) << 2));
        af[mt].u[0] = cvtpk(lo[0], lo[1]);
        af[mt].u[1] = cvtpk(lo[2], lo[3]);
        af[mt].u[2] = cvtpk(hi[0], hi[1]);
        af[mt].u[3] = cvtpk(hi[2], hi[3]);
      }
#pragma unroll
      for (int nt = 0; nt < 4; ++nt) {
        const int jj = (wc << 6) + (nt << 4) + c15;
        const bf16x8 bb = *(const bf16x8*)(wt + (jj << 6) + ((ch ^ (jj & 7)) << 3));
#pragma unroll
        for (int mt = 0; mt < 4; ++mt)
          acc[mt][nt] = __builtin_amdgcn_mfma_f32_16x16x32_bf16(af[mt].v, bb, acc[mt][nt], 0, 0, 0);
      }
    }
  }
  // epilogue: bias+relu, bag-dot partial, bf16 pack-pairs + dword stores
  float bias[4], wb0[4], wb1[4];
#pragma unroll
  for (int nt = 0; nt < 4; ++nt) {
    const int colg = col0 + (wc << 6) + (nt << 4) + c15;
    bias[nt] = bc[colg];
    wb0[nt] = Wbag[colg];
    wb1[nt] = Wbag[L + colg];
  }
#pragma unroll
  for (int mt = 0; mt < 4; ++mt) {
#pragma unroll
    for (int r = 0; r < 4; ++r) {
      const int rowg = row0 + (wr << 6) + (mt << 4) + (q << 2) + r;
      float tp0 = 0.f, tp1 = 0.f;
#pragma unroll
      for (int nt = 0; nt < 4; ++nt) {
        const int colg = col0 + (wc << 6) + (nt << 4) + c15;
        float v = acc[mt][nt][r] + bias[nt];
        v = v > 0.f ? v : 0.f;
        tp0 += v * wb0[nt];
        tp1 += v * wb1[nt];
        const unsigned short hb = f2bf(v);
        const unsigned short ob = (unsigned short)__shfl_xor((int)hb, 1, 64);
        if (!(lane & 1)) {
          *(unsigned*)(hB + (size_t)rowg * L + colg) = (unsigned)hb | ((unsigned)ob << 16);
        }
      }
#pragma unroll
      for (int off = 1; off < 16; off <<= 1) {
        tp0 += __shfl_xor(tp0, off, 64);
        tp1 += __shfl_xor(tp1, off, 64);
      }
      if (c15 == 0) {
        atomicAdd(&tws[(rowg << 1)], tp0);
        atomicAdd(&tws[(rowg << 1) + 1], tp1);
      }
    }
  }
}

// ------------- K2: a||b GEMM + tanh/sigmoid + (a*b)@Wa^T partial -> atomic A
// m97-shape: 128 rows x 64 D-dims x {a,b} per block, 4 waves (2x2) of 64x64
// (nt 0,1 = a-cols, nt 2,3 = b-cols of the SAME d's -> epilogue pairing stays
// in-thread).  BK=64, 8 K-steps, LDS 32KB -> 4 blocks/CU.
__global__ __launch_bounds__(256, 4) void k2_gemm2(const unsigned short* __restrict__ hB,
                                                   const unsigned short* __restrict__ W2B,
                                                   const float* __restrict__ bv,
                                                   const float* __restrict__ bu,
                                                   const float* __restrict__ Wa,
                                                   float* __restrict__ Aws) {
  __shared__ __align__(16) unsigned short hs[128 * 64];   // 16KB
  __shared__ __align__(16) unsigned short wt[128 * 64];   // 16KB: 64 Wv-rows + 64 Wu-rows
  const int tid = threadIdx.x, lane = tid & 63, wv = tid >> 6;
  const int dbk = blockIdx.x & 3;          // 4 d-tiles of 64
  const int rbk = blockIdx.x >> 2;         // 1024 row-tiles
  const int row0 = rbk << 7;
  const int d0 = dbk << 6;
  const int wr = wv >> 1, wc = wv & 1;
  const int q = lane >> 4, c15 = lane & 15;

  f32x4 acc[4][4];                         // nt 0,1 = a; nt 2,3 = b
#pragma unroll
  for (int i = 0; i < 4; ++i)
#pragma unroll
    for (int j = 0; j < 4; ++j) acc[i][j] = {0.f, 0.f, 0.f, 0.f};

  for (int kk = 0; kk < L; kk += 64) {
    __syncthreads();
#pragma unroll
    for (int i = 0; i < 4; ++i) {
      const int g = (wv << 2) + i;
      const int slot = (g << 6) + lane;
      const int j = slot >> 3;
      const int s = slot & 7;
      const int k8 = s ^ (j & 7);
      GLDS16(hB + (size_t)(row0 + j) * L + kk + (k8 << 3), hs + (g << 9));
    }
#pragma unroll
    for (int i = 0; i < 4; ++i) {
      const int g = (wv << 2) + i;
      const int slot = (g << 6) + lane;
      const int j = slot >> 3;
      const int s = slot & 7;
      const int k8 = s ^ (j & 7);
      const int w2row = (j < 64) ? (d0 + j) : (DD + d0 + (j - 64));
      GLDS16(W2B + (size_t)w2row * L + kk + (k8 << 3), wt + (g << 9));
    }
    __syncthreads();
#pragma unroll
    for (int ks = 0; ks < 2; ++ks) {
      const int ch = (ks << 2) + q;
      bf16x8 af[4];
#pragma unroll
      for (int mt = 0; mt < 4; ++mt) {
        const int rr = (wr << 6) + (mt << 4) + c15;
        af[mt] = *(const bf16x8*)(hs + (rr << 6) + ((ch ^ (rr & 7)) << 3));
      }
#pragma unroll
      for (int nt = 0; nt < 4; ++nt) {
        // nt 0,1 -> a (wt rows 0..63); nt 2,3 -> b (wt rows 64..127), same d's
        const int jj = ((nt >> 1) << 6) + (wc << 5) + ((nt & 1) << 4) + c15;
        const bf16x8 bb = *(const bf16x8*)(wt + (jj << 6) + ((ch ^ (jj & 7)) << 3));
#pragma unroll
        for (int mt = 0; mt < 4; ++mt)
          acc[mt][nt] = __builtin_amdgcn_mfma_f32_16x16x32_bf16(af[mt], bb, acc[mt][nt], 0, 0, 0);
      }
    }
  }
  // epilogue: ab = tanh(a+bv)*sig(b+bu); partials onto Wa rows 0/1
  float wa0[2], wa1[2], bvv[2], buv[2];
#pragma unroll
  for (int nt = 0; nt < 2; ++nt) {
    const int d = d0 + (wc << 5) + (nt << 4) + c15;
    wa0[nt] = Wa[d]; wa1[nt] = Wa[DD + d];
    bvv[nt] = bv[d]; buv[nt] = bu[d];
  }
#pragma unroll
  for (int mt = 0; mt < 4; ++mt) {
#pragma unroll
    for (int r = 0; r < 4; ++r) {
      const int rowg = row0 + (wr << 6) + (mt << 4) + (q << 2) + r;
      float p0 = 0.f, p1 = 0.f;
#pragma unroll
      for (int nt = 0; nt < 2; ++nt) {
        const float av = ftanh(acc[mt][nt][r] + bvv[nt]);
        const float bx = fsig(acc[mt][nt + 2][r] + buv[nt]);
        const float ab = av * bx;
        p0 += ab * wa0[nt];
        p1 += ab * wa1[nt];
      }
#pragma unroll
      for (int off = 1; off < 16; off <<= 1) {
        p0 += __shfl_xor(p0, off, 64);
        p1 += __shfl_xor(p1, off, 64);
      }
      if (c15 == 0) {
        atomicAdd(&Aws[(rowg << 1)], p0);
        atomicAdd(&Aws[(rowg << 1) + 1], p1);
      }
    }
  }
}

// ------ K3a: elementwise: A=Aws+ba -> out, exp-sums z/s, key min/max
__global__ void k3a_elem(const float* __restrict__ Aws, const float* __restrict__ tws,
                         const float* __restrict__ ba, const int* __restrict__ lblp,
                         float* __restrict__ out,
                         float* __restrict__ scalF, unsigned* __restrict__ scalU) {
  const int row = blockIdx.x * 256 + threadIdx.x;
  const int lane = threadIdx.x & 63;
  const float2 Ap = ((const float2*)Aws)[row];
  const float2 tp = ((const float2*)tws)[row];
  const float A0 = Ap.x + ba[0];
  const float A1 = Ap.y + ba[1];
  out[4 + row] = A0;
  out[4 + NROWS + row] = A1;
  const float e0 = __expf(A0), e1 = __expf(A1);
  float z0 = e0, z1 = e1, s0 = e0 * tp.x, s1 = e1 * tp.y;
  const int lbl = *lblp;
  unsigned u = encf(lbl ? A1 : A0);
  unsigned umin = u, umax = u;
#pragma unroll
  for (int off = 1; off < 64; off <<= 1) {
    z0 += __shfl_xor(z0, off, 64);
    z1 += __shfl_xor(z1, off, 64);
    s0 += __shfl_xor(s0, off, 64);
    s1 += __shfl_xor(s1, off, 64);
    const unsigned om = (unsigned)__shfl_xor((int)umin, off, 64);
    const unsigned oM = (unsigned)__shfl_xor((int)umax, off, 64);
    umin = umin < om ? umin : om;
    umax = umax > oM ? umax : oM;
  }
  if (lane == 0) {
    atomicAdd(&scalF[0], z0); atomicAdd(&scalF[1], z1);
    atomicAdd(&scalF[2], s0); atomicAdd(&scalF[3], s1);
    atomicMin(&scalU[0], umin);
    atomicMax(&scalU[1], umax);
  }
}

// ------ K3b: linear-bin histogram with per-block LDS pre-aggregation
__global__ __launch_bounds__(1024) void k3b_hist(const float* __restrict__ out,
                                                 const int* __restrict__ lblp,
                                                 const unsigned* __restrict__ scalU,
                                                 unsigned* __restrict__ hist) {
  __shared__ unsigned lh[NBINS];
  const int tid = threadIdx.x;
  for (int i = tid; i < NBINS; i += 1024) lh[i] = 0u;
  __syncthreads();
  const int lbl = *lblp;
  const int row = blockIdx.x * 1024 + tid;
  const float A = out[4 + (size_t)lbl * NROWS + row];
  const float mn = decf(scalU[0]);
  const float mx = decf(scalU[1]);
  const float scale = (mx > mn) ? (float)(NBINS - 1) / (mx - mn) : 0.f;
  int bin = (int)((A - mn) * scale);
  bin = bin < 0 ? 0 : (bin > NBINS - 1 ? NBINS - 1 : bin);
  atomicAdd(&lh[bin], 1u);
  __syncthreads();
  for (int i = tid; i < NBINS; i += 1024) {
    const unsigned c = lh[i];
    if (c) atomicAdd(&hist[i], c);
  }
}

// -------- K4: hist scan -> threshold bins; bag logits + y_proba -> out[0..3]
__global__ void k4_scan(const unsigned* __restrict__ hist,
                        const float* __restrict__ scalF,
                        unsigned* __restrict__ scalU,
                        const float* __restrict__ bbag,
                        float* __restrict__ out) {
  __shared__ unsigned csum[256];
  const int t = threadIdx.x;
  unsigned s = 0;
  for (int b = 0; b < 64; ++b) s += hist[t * 64 + b];
  csum[t] = s;
  __syncthreads();
  if (t == 0) {
    unsigned acc = 0; int ch = 255;
    for (; ch > 0; --ch) { if (acc + csum[ch] >= NI) break; acc += csum[ch]; }
    unsigned binHi = 0;
    for (int b = ch * 64 + 63; b >= ch * 64; --b) { acc += hist[b]; if (acc >= NI) { binHi = (unsigned)b; break; } }
    scalU[6] = binHi;
    acc = 0; int cl = 0;
    for (; cl < 255; ++cl) { if (acc + csum[cl] >= NI) break; acc += csum[cl]; }
    unsigned binLo = NBINS - 1;
    for (int b = cl * 64; b < cl * 64 + 64; ++b) { acc += hist[b]; if (acc >= NI) { binLo = (unsigned)b; break; } }
    scalU[7] = binLo;
    const float l0 = scalF[2] / scalF[0] + bbag[0];
    const float l1 = scalF[3] / scalF[1] + bbag[1];
    const float m = fmaxf(l0, l1);
    const float e0 = __expf(l0 - m), e1 = __expf(l1 - m);
    const float inv = 1.0f / (e0 + e1);
    out[0] = l0; out[1] = l1; out[2] = e0 * inv; out[3] = e1 * inv;
  }
}

// ----------------------------- K5: collect top/bottom candidates by bin
__global__ void k5_collect(const float* __restrict__ out,
                           const int* __restrict__ lblp,
                           unsigned* __restrict__ scalU,
                           unsigned* __restrict__ chK, unsigned* __restrict__ chI,
                           unsigned* __restrict__ clK, unsigned* __restrict__ clI) {
  const int binHi = (int)scalU[6], binLo = (int)scalU[7];
  const float mn = decf(scalU[0]);
  const float mx = decf(scalU[1]);
  const float scale = (mx > mn) ? (float)(NBINS - 1) / (mx - mn) : 0.f;
  const int lbl = *lblp;
  const float* Ap = out + 4 + (size_t)lbl * NROWS;
  const int n = blockIdx.x * 256 + threadIdx.x;
  const float A = Ap[n];
  int bin = (int)((A - mn) * scale);
  bin = bin < 0 ? 0 : (bin > NBINS - 1 ? NBINS - 1 : bin);
  const unsigned u = encf(A);
  if (bin >= binHi) { unsigned p = atomicAdd(&scalU[4], 1u); if (p < CAP) { chK[p] = u; chI[p] = (unsigned)n; } }
  if (bin <= binLo) { unsigned p = atomicAdd(&scalU[5], 1u); if (p < CAP) { clK[p] = u; clI[p] = (unsigned)n; } }
}

// -------- K6: exact rank selection + instance logits + SmoothTop1SVM loss
__global__ __launch_bounds__(256) void k6_loss(const unsigned* __restrict__ scalU,
                                               const unsigned* __restrict__ chK, const unsigned* __restrict__ chI,
                                               const unsigned* __restrict__ clK, const unsigned* __restrict__ clI,
                                               const unsigned short* __restrict__ hB,
                                               const float* __restrict__ Winst,
                                               const float* __restrict__ binst,
                                               const int* __restrict__ lblp,
                                               float* __restrict__ out) {
  __shared__ unsigned kH[CAP], iH[CAP], kL[CAP], iL[CAP];
  __shared__ int selT[NI], selB[NI];
  __shared__ float lossA[256];
  const int t = threadIdx.x;
  const int lbl = *lblp;
  const unsigned cH = scalU[4], cL = scalU[5];
  const int nH = (int)(cH < CAP ? cH : CAP);
  const int nL = (int)(cL < CAP ? cL : CAP);
  if (t < NI) { selT[t] = 0; selB[t] = 0; }
  for (int i = t; i < nH; i += 256) { kH[i] = chK[i]; iH[i] = chI[i]; }
  for (int i = t; i < nL; i += 256) { kL[i] = clK[i]; iL[i] = clI[i]; }
  __syncthreads();
  for (int c = t; c < nH; c += 256) {
    const unsigned k = kH[c], id = iH[c];
    int rank = 0;
    for (int j = 0; j < nH; ++j) rank += (kH[j] > k) || (kH[j] == k && iH[j] < id);
    if (rank < NI) selT[rank] = (int)id;
  }
  for (int c = t; c < nL; c += 256) {
    const unsigned k = kL[c], id = iL[c];
    int rank = 0;
    for (int j = 0; j < nL; ++j) rank += (kL[j] < k) || (kL[j] == k && iL[j] < id);
    if (rank < NI) selB[rank] = (int)id;
  }
  __syncthreads();
  float loss = 0.f;
  if (t < 2 * NI) {
    const int idx = (t < NI) ? selT[t] : selB[t - NI];
    const int target = (t < NI) ? 1 : 0;
    const unsigned short* hp = hB + (size_t)idx * L;
    const float* w0 = Winst + (size_t)lbl * 2 * L;
    const float* w1 = w0 + L;
    float l0 = binst[lbl * 2 + 0], l1 = binst[lbl * 2 + 1];
    for (int k = 0; k < L; ++k) {
      const float hv = bf2f(hp[k]);
      l0 += hv * w0[k];
      l1 += hv * w1[k];
    }
    const float z0 = l0 + (target ? 1.0f : 0.0f);
    const float z1 = l1 + (target ? 0.0f : 1.0f);
    const float m = fmaxf(z0, z1);
    const float lse = m + logf(__expf(z0 - m) + __expf(z1 - m));
    loss = lse - (target ? l1 : l0);
  }
  lossA[t] = loss;
  __syncthreads();
  for (int sft = 128; sft; sft >>= 1) {
    if (t < sft) lossA[t] += lossA[t + sft];
    __syncthreads();
  }
  if (t == 0) out[4 + 2 * NROWS] = lossA[0] / 100.0f;
}

extern "C" void kernel_launch(void* const* d_in, const int* in_sizes, int n_in,
                              void* d_out, int out_size, void* d_ws, size_t ws_size,
                              hipStream_t stream) {
  const float* x     = (const float*)d_in[0];
  const int*   lbl   = (const int*)d_in[1];
  const float* Wc    = (const float*)d_in[2];
  const float* bc    = (const float*)d_in[3];
  const float* Wv    = (const float*)d_in[4];
  const float* bv    = (const float*)d_in[5];
  const float* Wu    = (const float*)d_in[6];
  const float* bu    = (const float*)d_in[7];
  const float* Wa    = (const float*)d_in[8];
  const float* ba    = (const float*)d_in[9];
  const float* Winst = (const float*)d_in[10];
  const float* binst = (const float*)d_in[11];
  const float* Wbag  = (const float*)d_in[12];
  const float* bbag  = (const float*)d_in[13];
  float* out = (float*)d_out;
  char* ws = (char*)d_ws;

  unsigned short* hB   = (unsigned short*)(ws);                  // 134217728 B
  unsigned short* WcB  = (unsigned short*)(ws + 134217728LL);    // 1048576 B
  unsigned short* W2B  = (unsigned short*)(ws + 135266304LL);    // 524288 B
  float*          Aws  = (float*)(ws + 135790592LL);             // 1048576 B
  float*          tws  = (float*)(ws + 136839168LL);             // 1048576 B
  unsigned*       hist = (unsigned*)(ws + 137887744LL);          // 65536 B
  float*          scalF= (float*)(ws + 137953280LL);             // 64 B
  unsigned*       scalU= (unsigned*)(ws + 137953344LL);          // 64 B
  unsigned*       chK  = (unsigned*)(ws + 137953408LL);          // 4*CAP*4 B
  unsigned*       chI  = chK + CAP;
  unsigned*       clK  = chI + CAP;
  unsigned*       clI  = clK + CAP;

  k0_init<<<2048, 256, 0, stream>>>(Wc, Wv, Wu, WcB, W2B, Aws, tws, hist, scalF, scalU);
  k1_gemm1<<<4096, 256, 0, stream>>>(x, WcB, bc, Wbag, hB, tws);
  k2_gemm2<<<4096, 256, 0, stream>>>(hB, W2B, bv, bu, Wa, Aws);
  k3a_elem<<<512, 256, 0, stream>>>(Aws, tws, ba, lbl, out, scalF, scalU);
  k3b_hist<<<128, 1024, 0, stream>>>(out, lbl, scalU, hist);
  k4_scan<<<1, 256, 0, stream>>>(hist, scalF, scalU, bbag, out);
  k5_collect<<<512, 256, 0, stream>>>(out, lbl, scalU, chK, chI, clK, clI);
  k6_loss<<<1, 256, 0, stream>>>(scalU, chK, chI, clK, clI, hB, Winst, binst, lbl, out);
}